// Round 1
// baseline (291.484 us; speedup 1.0000x reference)
//
#include <hip/hip_runtime.h>
#include <math.h>

#define O_  32
#define I_  32
#define K_  13
#define N_  4096
#define IK  (I_ * K_)     // 416
#define OIK (O_ * IK)     // 13312
#define NB  4             // n's per block

typedef float f32x4 __attribute__((ext_vector_type(4)));

// One LDS gather + one barrier per NB n's, then a pure nontemporal mask
// stream with W held in registers for the whole block.
// Changes vs 290.4 µs baseline:
//  - wg[13] precompute removed (values were single-use; -52 VGPRs of live state)
//  - __launch_bounds__(256, 4): cap VGPRs at 128 so 4 waves/SIMD resident
//    (entire 1024-block grid co-resident in one pass).
__global__ __launch_bounds__(256, 4) void plaq_kernel(
    const float* __restrict__ x,      // (I, N)
    const float* __restrict__ W,      // (O, I, K)
    const float* __restrict__ b,      // (O,)
    const float* __restrict__ mask,   // (N, O, I, K)
    const int*   __restrict__ shifts, // (N, K)
    float* __restrict__ out)          // (O, N)
{
    __shared__ __align__(16) float g_lds[NB][IK];
    const int n0  = blockIdx.x * NB;
    const int tid = threadIdx.x;

    // Gather g[nl][i*13+k] = x[i*N + shifts[(n0+nl)*13+k]]  (1664 elems).
    for (int idx = tid; idx < NB * IK; idx += 256) {
        int nl = idx / IK;
        int r  = idx - nl * IK;
        int i  = r / K_;
        int k  = r - i * K_;
        int s  = shifts[(n0 + nl) * K_ + k];
        g_lds[nl][r] = x[i * N_ + s];
    }

    // Hoist W into registers while the gather is in flight (independent).
    const int o  = tid >> 3;
    const int s8 = tid & 7;
    const f32x4* w4 = (const f32x4*)(W + o * IK);
    f32x4 w[13];
#pragma unroll
    for (int m = 0; m < 13; ++m) w[m] = w4[s8 + 8 * m];
    const float bo = b[o];

    __syncthreads();

    const float scale = (float)((2.0 + 2.0 * M_E) / (M_E - 1.0));

    for (int nl = 0; nl < NB; ++nl) {
        const int n = n0 + nl;
        const f32x4* m4 = (const f32x4*)(mask + (size_t)n * OIK + o * IK);
        const f32x4* g4 = (const f32x4*)(&g_lds[nl][0]);

        // Hot loop: one nontemporal 16B mask load, one LDS 16B read,
        // 4 muls + 4 FMAs per iteration. wg is loop-local (short live range)
        // instead of a 52-VGPR precomputed array.
        float a0 = 0.f, a1 = 0.f, a2 = 0.f, a3 = 0.f;
#pragma unroll
        for (int m = 0; m < 13; ++m) {
            f32x4 mv = __builtin_nontemporal_load(&m4[s8 + 8 * m]);
            f32x4 wg = w[m] * g4[s8 + 8 * m];
            a0 = fmaf(mv.x, wg.x, a0);
            a1 = fmaf(mv.y, wg.y, a1);
            a2 = fmaf(mv.z, wg.z, a2);
            a3 = fmaf(mv.w, wg.w, a3);
        }
        float acc = (a0 + a1) + (a2 + a3);

        // Reduce across the 8 lanes sharing this o (within one wave).
        acc += __shfl_down(acc, 4);
        acc += __shfl_down(acc, 2);
        acc += __shfl_down(acc, 1);

        if (s8 == 0) {
            float y  = acc + bo;
            float sg = 1.0f / (1.0f + __expf(-y));
            out[o * N_ + n] = (sg - 0.5f) * scale;
        }
    }
}

extern "C" void kernel_launch(void* const* d_in, const int* in_sizes, int n_in,
                              void* d_out, int out_size, void* d_ws, size_t ws_size,
                              hipStream_t stream) {
    const float* x      = (const float*)d_in[0];
    const float* Wconv  = (const float*)d_in[1];
    const float* bconv  = (const float*)d_in[2];
    const float* mask   = (const float*)d_in[3];
    const int*   shifts = (const int*)d_in[4];
    float* out = (float*)d_out;

    plaq_kernel<<<N_ / NB, 256, 0, stream>>>(x, Wconv, bconv, mask, shifts, out);
}